// Round 8
// baseline (99.522 us; speedup 1.0000x reference)
//
#include <hip/hip_runtime.h>

// B=2, Hi=Wi=64, Di=32, C=16, F=8, strides (2,2,2), k=3x3x3, Ho=Wo=128, Do=64.
constexpr int Bc  = 2;
constexpr int HiC = 64, WiC = 64, DiC = 32;
constexpr int Cc  = 16, Fc  = 8;
constexpr int HoC = 128, WoC = 128, DoC = 64;

constexpr int SLAB_SHORTS = DiC * Cc;                  // 512 shorts = 1 KiB slab
constexpr int NSLAB       = 10;                        // 2 hi rows x 5 wi cols
constexpr int BUF_SHORTS  = NSLAB * SLAB_SHORTS + 8;   // slabs + 16 B zero block
constexpr int ZOFF        = NSLAB * SLAB_SHORTS * 2;   // zero block byte offset (per buffer)

typedef __attribute__((ext_vector_type(8))) short short8;   // 8 bf16 = A/B frag
typedef __attribute__((ext_vector_type(4))) float f32x4;    // MFMA accumulator

__device__ alignas(16) const float FZERO[8] = {0, 0, 0, 0, 0, 0, 0, 0};

__device__ __forceinline__ unsigned pk2(float x, float y) {   // RNE f32x2 -> bf16x2
    unsigned ux = __float_as_uint(x), uy = __float_as_uint(y);
    ux += ((ux >> 16) & 1u) + 0x7FFFu;
    uy += ((uy >> 16) & 1u) + 0x7FFFu;
    return (ux >> 16) | (uy & 0xFFFF0000u);
}
__device__ __forceinline__ short8 pack8(float4 a, float4 b) {
    union { unsigned u[4]; short8 s; } r;
    r.u[0] = pk2(a.x, a.y); r.u[1] = pk2(a.z, a.w);
    r.u[2] = pk2(b.x, b.y); r.u[3] = pk2(b.z, b.w);
    return r.s;
}

constexpr int KHT[4][4] = {{1,0,0,0},{1,1,0,0},{0,2,0,0},{0,0,2,2}};
constexpr int KWT[4][4] = {{1,0,0,0},{0,2,0,0},{1,1,0,0},{0,2,0,2}};

// Round 16: persistent blocks. r5-r7 evidence: sconv ~45us with ALL pipes idle
// (MFMA 2.7%, VALU 13%, HBM 20%, 3% issue-slot utilization) and four data-path
// interventions null -> per-block FIXED overhead (preamble/cold-I/staging ramp)
// paid 2048x is the suspect. This kernel: grid 512 (2/CU), each block loops
// over 4 row-pairs, double-buffered slab staging (1 barrier/iter), B-frags
// built ONCE per block (r-independent). Math identical to round-7 version.

// B-fragment build, hoisted out of the r-loop (kern-only; one call per block).
template<int CLS>
__device__ __forceinline__ void buildB(const float* __restrict__ kern, int lane,
                                       short8* __restrict__ bE,
                                       short8* __restrict__ bO) {
    constexpr int NP = (CLS == 0) ? 1 : ((CLS == 3) ? 4 : 2);
    constexpr int OP = (NP + 1) / 2;
    const int quad = lane >> 4, n = lane & 15;
    const int half = quad >> 1, chalf = quad & 1;
    #pragma unroll
    for (int p = 0; p < NP; ++p) {
        const int kp = KHT[CLS][p] * 3 + KWT[CLS][p];
        const float* wp = (n < Fc)
            ? kern + (kp * 3 + 2 * half) * 128 + n * 16 + chalf * 8 : FZERO;
        bE[p] = pack8(*(const float4*)wp, *(const float4*)(wp + 4));
    }
    #pragma unroll
    for (int pp = 0; pp < OP; ++pp) {
        const int  PA   = (2 * pp < NP) ? 2 * pp : 0;
        const bool hasB = (2 * pp + 1) < NP;
        const int  PB   = hasB ? (2 * pp + 1) : 0;
        const int kpa = KHT[CLS][PA] * 3 + KWT[CLS][PA];
        const int kpb = KHT[CLS][PB] * 3 + KWT[CLS][PB];
        const int kp  = half ? kpb : kpa;
        const bool v  = (n < Fc) && (!half || hasB);
        const float* wp = v ? kern + (kp * 3 + 1) * 128 + n * 16 + chalf * 8 : FZERO;
        bO[pp] = pack8(*(const float4*)wp, *(const float4*)(wp + 4));
    }
}

// Wave = 4 same-parity columns of one output row (MFMA packing & layouts as
// verified round-7/8; tap batching as round-15).
template<int CLS>
__device__ __forceinline__ void doCols(const short* __restrict__ slabs,
                                       const int*   __restrict__ bp,
                                       const short8* __restrict__ bE,
                                       const short8* __restrict__ bO,
                                       float*       __restrict__ out,
                                       float*       __restrict__ ldsw,
                                       int b, int ho, int wo0, int wi0, int lane) {
    constexpr int NP = (CLS == 0) ? 1 : ((CLS == 3) ? 4 : 2);
    constexpr int OP = (NP + 1) / 2;

    const int quad = lane >> 4, n = lane & 15;
    const int half = quad >> 1, chalf = quad & 1;   // k-half, channel-half
    const int chalfB = chalf * 16;                  // byte offset within di row

    // ---- phase 1: ALL scalar loads for all 4 columns ----
    int colx[4], bpcol[4], bpgr[4][NP], pxo[4][NP]; bool pvs[4][NP];
    #pragma unroll
    for (int cc = 0; cc < 4; ++cc) {
        const int wo = wo0 + 2 * cc;
        colx[cc]  = __builtin_amdgcn_readfirstlane((b * HoC + ho) * WoC + wo);
        bpcol[cc] = bp[colx[cc]];                    // uniform -> s_load
        #pragma unroll
        for (int p = 0; p < NP; ++p) {
            const int kh = KHT[CLS][p], kw = KWT[CLS][p];
            int hi = (ho + 1 - kh) >> 1; hi = hi > HiC - 1 ? HiC - 1 : hi;
            int wi = (wo + 1 - kw) >> 1; wi = wi > WiC - 1 ? WiC - 1 : wi;
            pvs[cc][p] = (kh != 0 || ho + 1 < HoC) && (kw != 0 || wo + 1 < WoC);
            const int sidx =
                __builtin_amdgcn_readfirstlane((b * HoC + 2 * hi) * WoC + 2 * wi);
            bpgr[cc][p] = bp[sidx];                  // uniform -> s_load
            const int hidx = (kh == 0) ? 1 : 0;      // row r+1 = kh0, row r = kh1/2
            pxo[cc][p] = __builtin_amdgcn_readfirstlane(
                             (hidx * 5 + (wi - wi0)) << 10);   // LDS bytes
        }
    }

    // ---- phase 2: per column batched tap loads -> MFMA burst -> epilogue ----
    #pragma unroll
    for (int cc = 0; cc < 4; ++cc) {
        const int bp_col = bpcol[cc];
        const int q      = (bp_col + 1) & 1;
        const int baseE  = (bp_col + q + 1) >> 1;    // di(kd0) = baseE+m-bpg
        const int baseO  = (bp_col + 1 - q) >> 1;    // di(kd1) = baseO+m-bpg
        int sE[NP], sO[NP];
        #pragma unroll
        for (int p = 0; p < NP; ++p) {               // sentinel folds validity
            const int bpg = bpgr[cc][p] >> 1;
            sE[p] = pvs[cc][p] ? baseE - bpg : -100000;
            sO[p] = pvs[cc][p] ? baseO - bpg : -100000;
        }

        // batch A-fragment loads: independent ds_read_b128s, one lgkm drain.
        short8 aE[2][NP], aO[2][OP];
        #pragma unroll
        for (int g = 0; g < 2; ++g) {
            #pragma unroll
            for (int p = 0; p < NP; ++p) {           // E: kd = 2*half
                const int  di = sE[p] + 16 * g + n - half;
                const bool ok = (unsigned)di < (unsigned)DiC;
                const int  off = ok ? pxo[cc][p] + di * 32 + chalfB : ZOFF;
                aE[g][p] = *(const short8*)((const char*)slabs + off);
            }
            #pragma unroll
            for (int pp = 0; pp < OP; ++pp) {        // O: k-halves = two positions
                const int  PA   = (2 * pp < NP) ? 2 * pp : 0;
                const bool hasB = (2 * pp + 1) < NP;
                const int  PB   = hasB ? (2 * pp + 1) : 0;
                const int  sOs  = half ? (hasB ? sO[PB] : -100000) : sO[PA];
                const int  pxs  = half ? pxo[cc][PB] : pxo[cc][PA];
                const int  di = sOs + 16 * g + n;
                const bool ok = (unsigned)di < (unsigned)DiC;
                const int  off = ok ? pxs + di * 32 + chalfB : ZOFF;
                aO[g][pp] = *(const short8*)((const char*)slabs + off);
            }
        }

        f32x4 accE[2] = {{0.f,0.f,0.f,0.f},{0.f,0.f,0.f,0.f}};
        f32x4 accO[2] = {{0.f,0.f,0.f,0.f},{0.f,0.f,0.f,0.f}};
        #pragma unroll
        for (int g = 0; g < 2; ++g) {
            #pragma unroll
            for (int p = 0; p < NP; ++p)
                accE[g] = __builtin_amdgcn_mfma_f32_16x16x32_bf16(aE[g][p], bE[p], accE[g], 0, 0, 0);
            #pragma unroll
            for (int pp = 0; pp < OP; ++pp)
                accO[g] = __builtin_amdgcn_mfma_f32_16x16x32_bf16(aO[g][pp], bO[pp], accO[g], 0, 0, 0);
        }

        // Wave-private LDS transpose: C/D (row=quad*4+r, col=n) -> [do][f] rows.
        __builtin_amdgcn_wave_barrier();
        if (n < Fc) {
            #pragma unroll
            for (int g = 0; g < 2; ++g) {
                #pragma unroll
                for (int r = 0; r < 4; ++r) {
                    const int m2 = 16 * g + quad * 4 + r;
                    ldsw[(2 * m2 + q) * Fc + n]     = accE[g][r];
                    ldsw[(2 * m2 + 1 - q) * Fc + n] = accO[g][r];
                }
            }
        }
        __builtin_amdgcn_wave_barrier();
        float* outc = out + (size_t)colx[cc] * (DoC * Fc);
        *(float4*)(outc + lane * 8)     = *(const float4*)(ldsw + lane * 8);
        *(float4*)(outc + lane * 8 + 4) = *(const float4*)(ldsw + lane * 8 + 4);
        __builtin_amdgcn_wave_barrier();
    }
}

__global__ __launch_bounds__(256, 2)
void sconv_mfma(const float* __restrict__ img, const int* __restrict__ bp,
                const float* __restrict__ kern, float* __restrict__ out) {
    __shared__ short slabs2[2][BUF_SHORTS];            // 2 x (10 KiB + 16 B zeros)
    __shared__ float lds[4 * DoC * Fc];                // 8 KiB transpose scratch
    const int t = threadIdx.x, wv = t >> 6, lane = t & 63;
    const int b = blockIdx.z, rg = blockIdx.y;         // rg: 4 row-pairs each
    const int p  = wv & 1, hs = wv >> 1;               // wave = (ho-par, wo-par)
    const int wo0 = (blockIdx.x << 3) + p;
    const int wi0 = blockIdx.x << 2;                   // leftmost staged wi
    float* ldsw = lds + wv * (DoC * Fc);

    // B-fragments: kern-only, built ONCE per block (hoisted out of r-loop).
    short8 bE[4], bO[2];
    if (hs) { if (p) buildB<3>(kern, lane, bE, bO); else buildB<2>(kern, lane, bE, bO); }
    else    { if (p) buildB<1>(kern, lane, bE, bO); else buildB<0>(kern, lane, bE, bO); }

    if (t < 8) {                                       // 16 B zero block per buffer
        slabs2[0][NSLAB * SLAB_SHORTS + t] = 0;
        slabs2[1][NSLAB * SLAB_SHORTS + t] = 0;
    }

    for (int rr = 0; rr < 4; ++rr) {
        const int r  = (rg << 2) + rr;                 // row-pair {2r, 2r+1}
        const int ho = 2 * r + hs;
        short* sb = &slabs2[rr & 1][0];

        // cooperative staging w/ fused f32->bf16: 10 slabs (rows r, r+1).
        // Double-buffered: writing buf[rr&1] is safe — sync before compute rr-1
        // guaranteed all waves finished compute rr-2 (same buffer).
        const int hi0 = r;
        int hi1 = r + 1; if (hi1 > HiC - 1) hi1 = HiC - 1;
        #pragma unroll
        for (int k = 0; k < 3; ++k) {                  // s = wv, wv+4, wv+8
            const int s = wv + 4 * k;
            if (s < NSLAB) {
                const int hi = (s >= 5) ? hi1 : hi0;
                int wi = wi0 + ((s >= 5) ? s - 5 : s); if (wi > WiC - 1) wi = WiC - 1;
                const float* g = img + (((b * HiC + hi) * WiC + wi) << 9) + lane * 8;
                float4 v0 = *(const float4*)g;
                float4 v1 = *(const float4*)(g + 4);
                *(short8*)&sb[(s << 9) + lane * 8] = pack8(v0, v1);
            }
        }
        __syncthreads();

        if (hs) {
            if (p) doCols<3>(sb, bp, bE, bO, out, ldsw, b, ho, wo0, wi0, lane);
            else   doCols<2>(sb, bp, bE, bO, out, ldsw, b, ho, wo0, wi0, lane);
        } else {
            if (p) doCols<1>(sb, bp, bE, bO, out, ldsw, b, ho, wo0, wi0, lane);
            else   doCols<0>(sb, bp, bE, bO, out, ldsw, b, ho, wo0, wi0, lane);
        }
    }
}

extern "C" void kernel_launch(void* const* d_in, const int* in_sizes, int n_in,
                              void* d_out, int out_size, void* d_ws, size_t ws_size,
                              hipStream_t stream) {
    const float* images = (const float*)d_in[0];
    const int*   bp     = (const int*)d_in[1];
    const float* kern   = (const float*)d_in[2];
    float* out = (float*)d_out;
    (void)d_ws; (void)ws_size;   // ws untouched (poison fill is unconditional
                                 // anyway — round-2 lesson)

    dim3 grid(WoC / 8, 16, Bc), block(256);   // 16 x 16 x 2 = 512 blocks, 2/CU
    hipLaunchKernelGGL(sconv_mfma, grid, block, 0, stream,
                       images, bp, kern, out);
}